// Round 6
// baseline (262.037 us; speedup 1.0000x reference)
//
#include <hip/hip_runtime.h>
#include <math.h>

#define DIM    64
#define MAXT   16
#define SLICES 64
#define QB     128
#define CH     16            // selection chunk = 16 rows
#define CLCAP  2048
#define NEG_INF (-3.0e38f)
#define MARGIN 0.004f

typedef float f32x4 __attribute__((ext_vector_type(4)));
typedef _Float16 f16x8 __attribute__((ext_vector_type(8)));
typedef short s16x8 __attribute__((ext_vector_type(8)));
typedef unsigned short u16;

__device__ __forceinline__ u16 f2h(float f) {   // RNE f32->fp16 bits
  union { _Float16 h; u16 u; } c; c.h = (_Float16)f; return c.u;
}
__device__ __forceinline__ float h2f(u16 h) {
  union { u16 u; _Float16 h; } c; c.u = h; return (float)c.h;
}

__device__ __forceinline__ const float* row_src(int r, const float* __restrict__ mem,
                                                const float* __restrict__ emb,
                                                int wp, int N, int B) {
  int diff = r - wp; if (diff < 0) diff += N;
  return (diff < B) ? (emb + (size_t)diff * DIM) : (mem + (size_t)r * DIM);
}

__device__ __forceinline__ bool rank_below(float a_v, int a_i, float v, int id) {
  return (a_v < v) || (a_v == v && a_i > id);
}

__device__ __forceinline__ void insert_val(float (&lv)[MAXT], float v) {
#pragma unroll
  for (int k = MAXT - 1; k > 0; --k) {
    if (lv[k - 1] < v)      { lv[k] = lv[k - 1]; }
    else if (lv[k] < v)     { lv[k] = v;         }
  }
  if (lv[0] < v) lv[0] = v;
}

__device__ __forceinline__ void insert_pair(float (&lv)[MAXT], int (&li)[MAXT],
                                            float v, int id) {
#pragma unroll
  for (int k = MAXT - 1; k > 0; --k) {
    if (rank_below(lv[k - 1], li[k - 1], v, id)) { lv[k] = lv[k - 1]; li[k] = li[k - 1]; }
    else if (rank_below(lv[k], li[k], v, id))    { lv[k] = v;         li[k] = id;        }
  }
  if (rank_below(lv[0], li[0], v, id)) { lv[0] = v; li[0] = id; }
}

// ---------------- K1: normalize updated memory + queries -> fp16; inv-norms -
__global__ __launch_bounds__(256)
void prep_kernel(const float* __restrict__ mem, const float* __restrict__ emb,
                 const float* __restrict__ qry, const int* __restrict__ wpp,
                 float* __restrict__ rm, float* __restrict__ rq,
                 u16* __restrict__ Mn, u16* __restrict__ Qn,
                 int N, int B, int Q) {
  const int wp  = *wpp;
  const int row = blockIdx.x * 32 + (threadIdx.x >> 3);
  const int sub = threadIdx.x & 7;
  if (row >= N + Q) return;
  const float* src = (row < N) ? row_src(row, mem, emb, wp, N, B)
                               : (qry + (size_t)(row - N) * DIM);
  const float4* s4 = (const float4*)src + sub * 2;
  float4 a = s4[0], b = s4[1];
  float ss = a.x*a.x + a.y*a.y + a.z*a.z + a.w*a.w
           + b.x*b.x + b.y*b.y + b.z*b.z + b.w*b.w;
  ss += __shfl_xor(ss, 1);
  ss += __shfl_xor(ss, 2);
  ss += __shfl_xor(ss, 4);
  const float inv = 1.0f / fmaxf(sqrtf(ss), 1e-12f);
  uint4 o;
  o.x = (unsigned)f2h(a.x*inv) | ((unsigned)f2h(a.y*inv) << 16);
  o.y = (unsigned)f2h(a.z*inv) | ((unsigned)f2h(a.w*inv) << 16);
  o.z = (unsigned)f2h(b.x*inv) | ((unsigned)f2h(b.y*inv) << 16);
  o.w = (unsigned)f2h(b.z*inv) | ((unsigned)f2h(b.w*inv) << 16);
  u16* dst = (row < N) ? (Mn + (size_t)row * DIM + sub * 8)
                       : (Qn + (size_t)(row - N) * DIM + sub * 8);
  *(uint4*)dst = o;
  if (sub == 0) { if (row < N) rm[row] = inv; else rq[row - N] = inv; }
}

// ---------------- K2a: LDS-free fp16 MFMA -> per-(q,16-row-chunk) max (fp16)
// Swapped operands: D = mfma(A=mem rows, B=queries). Wave owns 2 of the 8
// chunk16-tiles per 128-row step (no cross-wave data reuse -> no LDS, no
// barriers); all 8 query subtiles live in regs. A-frags loaded straight from
// global (L2-resident: XCD-swizzled block mapping), register double-buffered.
__global__ __launch_bounds__(256, 3)
void chunkmax_kernel(const u16* __restrict__ Mn, const u16* __restrict__ Qn,
                     u16* __restrict__ Cmax, int N, int nch) {
  const int tid = threadIdx.x;
  const int w = tid >> 6, l = tid & 63;

  const int id = blockIdx.x + gridDim.x * blockIdx.y;   // 0..1023
  const int s  = (id & 7) * 8 + (id >> 7);              // slice, fixed per XCD
  const int qb = (id >> 3) & 15;
  const int q0 = qb * QB;
  const int slice_rows = N / SLICES;                    // 2048
  const int nc2 = slice_rows / 128;                     // 16
  const int row_base = s * slice_rows;

  // B fragments = queries: col = l&15, k = (l>>4)*8 + ks*32
  f16x8 qF[8][2];
#pragma unroll
  for (int j = 0; j < 8; ++j)
#pragma unroll
    for (int ks = 0; ks < 2; ++ks)
      qF[j][ks] = *(const f16x8*)(Qn + (size_t)(q0 + j*16 + (l & 15)) * DIM
                                      + ks*32 + (l >> 4)*8);

  // A-frag source address for (c2, tt, ks): row = base + c2*128 + (w*2+tt)*16 + (l&15)
  const size_t lrow = (size_t)(l & 15) * DIM + (l >> 4) * 8;
  const u16* Abase = Mn + (size_t)(row_base + w * 32) * DIM + lrow;

  f16x8 aC[2][2], aN[2][2];
#pragma unroll
  for (int tt = 0; tt < 2; ++tt)
#pragma unroll
    for (int ks = 0; ks < 2; ++ks)
      aC[tt][ks] = *(const f16x8*)(Abase + (size_t)tt*16*DIM + ks*32);

  for (int c2 = 0; c2 < nc2; ++c2) {
    if (c2 + 1 < nc2) {
      const u16* nb = Abase + (size_t)(c2 + 1) * 128 * DIM;
#pragma unroll
      for (int tt = 0; tt < 2; ++tt)
#pragma unroll
        for (int ks = 0; ks < 2; ++ks)
          aN[tt][ks] = *(const f16x8*)(nb + (size_t)tt*16*DIM + ks*32);
    }
#pragma unroll
    for (int j = 0; j < 8; ++j) {
      f32x4 a0 = {0.f, 0.f, 0.f, 0.f};
      f32x4 a1 = {0.f, 0.f, 0.f, 0.f};
      a0 = __builtin_amdgcn_mfma_f32_16x16x32_f16(aC[0][0], qF[j][0], a0, 0, 0, 0);
      a0 = __builtin_amdgcn_mfma_f32_16x16x32_f16(aC[0][1], qF[j][1], a0, 0, 0, 0);
      a1 = __builtin_amdgcn_mfma_f32_16x16x32_f16(aC[1][0], qF[j][0], a1, 0, 0, 0);
      a1 = __builtin_amdgcn_mfma_f32_16x16x32_f16(aC[1][1], qF[j][1], a1, 0, 0, 0);
      // chunk16 max: in-lane over 4 rows, then xor16 (ds_swizzle) + xor32
      float m0 = fmaxf(fmaxf(a0[0], a0[1]), fmaxf(a0[2], a0[3]));
      float m1 = fmaxf(fmaxf(a1[0], a1[1]), fmaxf(a1[2], a1[3]));
      m0 = fmaxf(m0, __int_as_float(__builtin_amdgcn_ds_swizzle(__float_as_int(m0), 0x401F)));
      m1 = fmaxf(m1, __int_as_float(__builtin_amdgcn_ds_swizzle(__float_as_int(m1), 0x401F)));
      m0 = fmaxf(m0, __shfl_xor(m0, 32));
      m1 = fmaxf(m1, __shfl_xor(m1, 32));
      if (l < 16) {
        const int q = q0 + j*16 + l;
        const unsigned pk = (unsigned)f2h(m0) | ((unsigned)f2h(m1) << 16);
        *(unsigned*)(Cmax + (size_t)q * nch + s*128 + c2*8 + w*2) = pk;
      }
    }
#pragma unroll
    for (int tt = 0; tt < 2; ++tt)
#pragma unroll
      for (int ks = 0; ks < 2; ++ks)
        aC[tt][ks] = aN[tt][ks];
  }
}

// ---------------- K2b: tau = (K-th largest chunk-max) - MARGIN; compact ids -
// one wave per query; fp16 maxes, group-gated scan.
__global__ __launch_bounds__(256)
void select_kernel(const u16* __restrict__ Cmax, u16* __restrict__ clist,
                   int* __restrict__ ccount, int nch, int K) {
  const int w = threadIdx.x >> 6, l = threadIdx.x & 63;
  const int q = blockIdx.x * 4 + w;
  const u16* row = Cmax + (size_t)q * nch;

  float lv[MAXT];
#pragma unroll
  for (int k = 0; k < MAXT; ++k) lv[k] = NEG_INF;

#pragma unroll 4
  for (int i = 0; i < 16; ++i) {
    s16x8 x = *(const s16x8*)(row + i*512 + l*8);
    float v[8];
#pragma unroll
    for (int e = 0; e < 8; ++e) v[e] = h2f((u16)x[e]);
    float mx = fmaxf(fmaxf(fmaxf(v[0], v[1]), fmaxf(v[2], v[3])),
                     fmaxf(fmaxf(v[4], v[5]), fmaxf(v[6], v[7])));
    if (mx > lv[MAXT - 1]) {
#pragma unroll
      for (int e = 0; e < 8; ++e)
        if (v[e] > lv[MAXT - 1]) insert_val(lv, v[e]);
    }
  }

  float mk = NEG_INF;
  for (int r = 0; r < K; ++r) {
    float bv = lv[0]; int bl = l;
#pragma unroll
    for (int it = 0; it < 6; ++it) {
      float ov = __shfl_xor(bv, 1 << it);
      int   ol = __shfl_xor(bl, 1 << it);
      if (ov > bv || (ov == bv && ol < bl)) { bv = ov; bl = ol; }
    }
    mk = bv;
    if (l == bl) {
#pragma unroll
      for (int k = 0; k < MAXT - 1; ++k) lv[k] = lv[k + 1];
      lv[MAXT - 1] = NEG_INF;
    }
  }
  const float tau = mk - MARGIN;

  u16* out = clist + (size_t)q * CLCAP;
  int cnt = 0;
#pragma unroll 4
  for (int i = 0; i < 16; ++i) {
    s16x8 x = *(const s16x8*)(row + i*512 + l*8);
    float v[8];
#pragma unroll
    for (int e = 0; e < 8; ++e) v[e] = h2f((u16)x[e]);
    float mx = fmaxf(fmaxf(fmaxf(v[0], v[1]), fmaxf(v[2], v[3])),
                     fmaxf(fmaxf(v[4], v[5]), fmaxf(v[6], v[7])));
    if (__ballot(mx >= tau) == 0ull) continue;
#pragma unroll
    for (int e = 0; e < 8; ++e) {
      const bool p = (v[e] >= tau);
      const unsigned long long b = __ballot(p);
      if (p) {
        const int pos = cnt + (int)__popcll(b & ((1ull << l) - 1ull));
        if (pos < CLCAP) out[pos] = (u16)(i*512 + l*8 + e);
      }
      cnt += (int)__popcll(b);
    }
  }
  if (l == 0) ccount[q] = (cnt > CLCAP) ? CLCAP : cnt;
}

// ---------------- K2c: exact fp32 rescore; one block (4 waves) per query ----
// Per wave-iter: stage one 16-row chunk (4 KB) into the wave's LDS buffer via
// global_load_lds with inverse-swizzled per-lane SOURCE (linear dest), then 4
// lanes per row broadcast-read the row and redundantly compute the UNCHANGED
// sequential fmaf chain (bit-exact vs prior rounds); insert gated to p==0.
// Double-buffered with s_waitcnt vmcnt(4).
__global__ __launch_bounds__(256)
void rescore_kernel(const float* __restrict__ mem, const float* __restrict__ emb,
                    const float* __restrict__ qry, const int* __restrict__ wpp,
                    const float* __restrict__ rm, const float* __restrict__ rq,
                    const u16* __restrict__ clist, const int* __restrict__ ccount,
                    float* __restrict__ out_retr, float* __restrict__ out_vals,
                    int N, int B, int Q, int K) {
  __shared__ float chS[4][2][1024];     // per-wave double buffer, 32 KB
  __shared__ float wvS[4 * MAXT];
  __shared__ int   wiS[4 * MAXT];
  __shared__ int   eiS[MAXT];
  const int tid = threadIdx.x;
  const int w = tid >> 6, l = tid & 63;
  const int q = blockIdx.x;
  const int wp = *wpp;

  float4 qv[16];
  {
    const float4* qr4 = (const float4*)(qry + (size_t)q * DIM);
#pragma unroll
    for (int d = 0; d < 16; ++d) qv[d] = qr4[d];
  }
  const float rqv = rq[q];
  const int cnt = ccount[q];
  const u16* cl = clist + (size_t)q * CLCAP;

  // staging geometry: instr i writes LDS 16B-blocks [i*64 + l] (linear dest);
  // blk -> (r = i*4 + (l>>4), xd = l&15); source block xs = xd ^ (r&7).
  const int xd = l & 15;

  float lv[MAXT]; int li[MAXT];
#pragma unroll
  for (int k = 0; k < MAXT; ++k) { lv[k] = NEG_INF; li[k] = 0x7fffffff; }

  const int r4 = l >> 2;                 // row owned (4 lanes each)
  const int rsw = r4 & 7;
  const bool p0 = ((l & 3) == 0);

  int buf = 0;
  // issue chunk ci into buffer b
  auto issue = [&](int ci, int b) {
    const int ch = (int)cl[ci];
#pragma unroll
    for (int i = 0; i < 4; ++i) {
      const int rr = i*4 + (l >> 4);
      const float* rp = row_src(ch * CH + rr, mem, emb, wp, N, B);
      __builtin_amdgcn_global_load_lds(
          (const __attribute__((address_space(1))) unsigned int*)(rp + ((xd ^ (rr & 7)) << 2)),
          (__attribute__((address_space(3))) unsigned int*)&chS[w][b][i * 256], 16, 0, 0);
    }
  };

  if (w < cnt) issue(w, 0);
  for (int ci = w; ci < cnt; ci += 4) {
    const bool more = (ci + 4 < cnt);
    if (more) issue(ci + 4, buf ^ 1);
    if (more) { asm volatile("s_waitcnt vmcnt(4)" ::: "memory"); }
    else      { asm volatile("s_waitcnt vmcnt(0)" ::: "memory"); }
    const int ch = (int)cl[ci];
    const int row = ch * CH + r4;
    const float* Lr = &chS[w][buf][r4 * 64];
    float acc = 0.f;
#pragma unroll
    for (int d4 = 0; d4 < 16; ++d4) {
      const float4 m4 = *(const float4*)(Lr + ((d4 ^ rsw) << 2));
      const float4 q4 = qv[d4];
      acc = fmaf(q4.x, m4.x, acc); acc = fmaf(q4.y, m4.y, acc);
      acc = fmaf(q4.z, m4.z, acc); acc = fmaf(q4.w, m4.w, acc);
    }
    const float vv = p0 ? acc * rqv * rm[row] : NEG_INF;
    const int  rid = p0 ? row : 0x7fffffff;
    if (rank_below(lv[MAXT - 1], li[MAXT - 1], vv, rid)) insert_pair(lv, li, vv, rid);
    buf ^= 1;
  }

  // per-wave drain: wave's top-K (sorted) -> LDS
  for (int r = 0; r < K; ++r) {
    float bv = lv[0]; int bi = li[0];
#pragma unroll
    for (int it = 0; it < 6; ++it) {
      float ov = __shfl_xor(bv, 1 << it);
      int   oi = __shfl_xor(bi, 1 << it);
      if (ov > bv || (ov == bv && oi < bi)) { bv = ov; bi = oi; }
    }
    if (li[0] == bi) {
#pragma unroll
      for (int k = 0; k < MAXT - 1; ++k) { lv[k] = lv[k + 1]; li[k] = li[k + 1]; }
      lv[MAXT - 1] = NEG_INF; li[MAXT - 1] = 0x7fffffff;
    }
    if (l == 0) { wvS[w*MAXT + r] = bv; wiS[w*MAXT + r] = bi; }
  }
  __syncthreads();

  if (w == 0) {
    int hp = 0;
    float hv = NEG_INF; int hi = 0x7fffffff;
    if (l < 4) { hv = wvS[l*MAXT]; hi = wiS[l*MAXT]; }
    for (int r = 0; r < K; ++r) {
      float bv = hv; int bi = hi; int bs = (l < 4) ? l : 0x7fffffff;
#pragma unroll
      for (int it = 0; it < 2; ++it) {
        float ov = __shfl_xor(bv, 1 << it);
        int   oi = __shfl_xor(bi, 1 << it);
        int   os = __shfl_xor(bs, 1 << it);
        if (ov > bv || (ov == bv && oi < bi)) { bv = ov; bi = oi; bs = os; }
      }
      if (l == 0) { out_vals[(size_t)q * K + r] = bv; eiS[r] = bi; }
      if (l < 4 && l == bs) {
        ++hp;
        if (hp < K) { hv = wvS[l*MAXT + hp]; hi = wiS[l*MAXT + hp]; }
        else        { hv = NEG_INF;          hi = 0x7fffffff;       }
      }
    }
  }
  __syncthreads();

  for (int e = tid; e < K * DIM; e += 256) {
    const int kk = e >> 6, d = e & 63;
    const float* mr = row_src(eiS[kk], mem, emb, wp, N, B);
    out_retr[((size_t)q * K + kk) * DIM + d] = mr[d];
  }
}

// ---------------- host launch ----------------
extern "C" void kernel_launch(void* const* d_in, const int* in_sizes, int n_in,
                              void* d_out, int out_size, void* d_ws, size_t ws_size,
                              hipStream_t stream) {
  const float* mem = (const float*)d_in[0];
  const float* emb = (const float*)d_in[1];
  const float* qry = (const float*)d_in[2];
  const int*   wpp = (const int*)d_in[3];

  const int N = in_sizes[0] / DIM;     // 131072
  const int B = in_sizes[1] / DIM;     // 4096
  const int Q = in_sizes[2] / DIM;     // 2048
  int K = out_size / (Q * (DIM + 1));  // 10
  if (K < 1) K = 1;
  if (K > MAXT) K = MAXT;
  const int nch = N / CH;              // 8192

  // ws: rm[N] | rq[Q] | Cmax[Q*nch] u16(fp16) | clist[Q*CLCAP] u16 | ccount[Q] | Mn | Qn
  float* rm    = (float*)d_ws;
  float* rq    = rm + N;
  u16*   Cmax  = (u16*)(rq + Q);
  u16*   clist = Cmax + (size_t)Q * nch;
  int*   ccount= (int*)(clist + (size_t)Q * CLCAP);
  u16*   Mn    = (u16*)(ccount + Q);
  u16*   Qn    = Mn + (size_t)N * DIM;

  float* out_retr = (float*)d_out;
  float* out_vals = (float*)d_out + (size_t)Q * K * DIM;

  prep_kernel<<<(N + Q) / 32, 256, 0, stream>>>(mem, emb, qry, wpp, rm, rq, Mn, Qn, N, B, Q);

  dim3 g2(Q / QB, SLICES);
  chunkmax_kernel<<<g2, 256, 0, stream>>>(Mn, Qn, Cmax, N, nch);

  select_kernel<<<Q / 4, 256, 0, stream>>>(Cmax, clist, ccount, nch, K);

  rescore_kernel<<<Q, 256, 0, stream>>>(mem, emb, qry, wpp, rm, rq, clist, ccount,
                                        out_retr, out_vals, N, B, Q, K);
}